// Round 3
// baseline (618.407 us; speedup 1.0000x reference)
//
#include <hip/hip_runtime.h>
#include <cstdint>

// ---- problem constants (MoEFeedForward: N=4096, D=1024, F=2048, E=8, top-2) ----
#define N_TOK 4096
#define D_MODEL 1024
#define D_FF 2048
#define N_EXP 8
#define PITCH 40   // padded LDS row pitch in bf16 elems (80 B): bank quad = (20r+4c)%32, 2-way max

// DTYPE: inputs fp32, output fp32 (reference dtypes). bf16 only inside the MFMA core.
typedef __bf16 bf16;
typedef __bf16 bf16x8 __attribute__((ext_vector_type(8)));
typedef float f32x4 __attribute__((ext_vector_type(4)));

typedef __attribute__((address_space(1))) void v1_t;
typedef __attribute__((address_space(3))) void v3_t;

// async global->LDS raw copy, 16B/lane; dest = wave-uniform base + lane*16
__device__ __forceinline__ void cp16(void* lds, const void* g) {
  __builtin_amdgcn_global_load_lds((v1_t*)g, (v3_t*)lds, 16, 0, 0);
}

__device__ __forceinline__ f32x4 mfma16(bf16x8 a, bf16x8 b, f32x4 c) {
  return __builtin_amdgcn_mfma_f32_16x16x32_bf16(a, b, c, 0, 0, 0);
}

__device__ __forceinline__ bf16x8 cvt8(float4 a, float4 b) {
  bf16x8 v;
  v[0] = (bf16)a.x; v[1] = (bf16)a.y; v[2] = (bf16)a.z; v[3] = (bf16)a.w;
  v[4] = (bf16)b.x; v[5] = (bf16)b.y; v[6] = (bf16)b.z; v[7] = (bf16)b.w;
  return v;
}

// ======================= router: fp32 logits -> softmax -> top2 -> expert lists ==============
__global__ __launch_bounds__(256) void router_kernel(
    const float* __restrict__ x, const float* __restrict__ wr,
    int* __restrict__ counts, int* __restrict__ ids, float* __restrict__ wts)
{
  const int token = blockIdx.x * 4 + (threadIdx.x >> 6);  // one wave per token
  const int lane  = threadIdx.x & 63;

  const float4* xrow = (const float4*)(x + (size_t)token * D_MODEL + lane * 16);
  float4 x0 = xrow[0], x1 = xrow[1], x2 = xrow[2], x3 = xrow[3];

  float logit[N_EXP];
#pragma unroll
  for (int e = 0; e < N_EXP; ++e) {
    const float4* wrow = (const float4*)(wr + e * D_MODEL + lane * 16);
    float4 w0 = wrow[0], w1 = wrow[1], w2 = wrow[2], w3 = wrow[3];
    float s = x0.x*w0.x + x0.y*w0.y + x0.z*w0.z + x0.w*w0.w
            + x1.x*w1.x + x1.y*w1.y + x1.z*w1.z + x1.w*w1.w
            + x2.x*w2.x + x2.y*w2.y + x2.z*w2.z + x2.w*w2.w
            + x3.x*w3.x + x3.y*w3.y + x3.z*w3.z + x3.w*w3.w;
#pragma unroll
    for (int m = 32; m >= 1; m >>= 1) s += __shfl_xor(s, m);
    logit[e] = fminf(fmaxf(s, -1e4f), 1e4f);   // reference CLAMP
  }

  if (lane == 0) {
    float mx = logit[0];
#pragma unroll
    for (int e = 1; e < N_EXP; ++e) mx = fmaxf(mx, logit[e]);
    float ex[N_EXP], sum = 0.f;
#pragma unroll
    for (int e = 0; e < N_EXP; ++e) { ex[e] = expf(logit[e] - mx); sum += ex[e]; }
    float p[N_EXP];
#pragma unroll
    for (int e = 0; e < N_EXP; ++e)
      p[e] = fminf(fmaxf(ex[e] / (sum + 1e-8f), 1e-8f), 1.0f);
    int e0 = 0;
#pragma unroll
    for (int e = 1; e < N_EXP; ++e) if (p[e] > p[e0]) e0 = e;
    int e1 = (e0 == 0) ? 1 : 0;
#pragma unroll
    for (int e = 0; e < N_EXP; ++e) if (e != e0 && p[e] > p[e1]) e1 = e;
    float p0 = p[e0], p1 = p[e1];
    float inv = 1.f / (p0 + p1 + 1e-8f);
    p0 *= inv; p1 *= inv;
    int l0 = atomicAdd(&counts[e0], 1);
    int l1 = atomicAdd(&counts[e1], 1);
    ids[e0 * N_TOK + l0] = token; wts[e0 * N_TOK + l0] = p0;
    ids[e1 * N_TOK + l1] = token; wts[e1 * N_TOK + l1] = p1;
  }
}

// ======================= tiny exclusive prefix over 8 counts =======================
__global__ void offsets_kernel(const int* __restrict__ counts, int* __restrict__ offsets) {
  if (threadIdx.x == 0) {
    int r = 0;
#pragma unroll
    for (int e = 0; e < N_EXP; ++e) { offsets[e] = r; r += counts[e]; }
  }
}

// ===== GEMM1: gathered x(fp32) @ Wgu^T(fp32) via bf16 MFMA -> SwiGLU -> H (bf16) =====
// block tile 128x128, BK=32; staging converts fp32->bf16 in-register into padded LDS
__global__ __launch_bounds__(256, 2) void gemm1_kernel(
    const float* __restrict__ x, const float* __restrict__ wgu,
    const int* __restrict__ counts, const int* __restrict__ offsets,
    const int* __restrict__ ids, bf16* __restrict__ H)
{
  const int e = blockIdx.z;
  const int cnt = counts[e];
  const int row0 = blockIdx.y * 128;
  if (row0 >= cnt) return;
  const int c0 = blockIdx.x * 128;       // hidden col tile in [0, 2048)

  __shared__ bf16 lA [128 * PITCH];
  __shared__ bf16 lBg[128 * PITCH];
  __shared__ bf16 lBu[128 * PITCH];

  const int tid  = threadIdx.x;
  const int lane = tid & 63;
  const int wave = tid >> 6;

  // staging map: thread covers rows (sr, sr+64), k chunk of 8 floats at sk
  const int sr = tid >> 2;               // 0..63
  const int sk = (tid & 3) * 8;          // 0,8,16,24

  const int* ide = ids + e * N_TOK;
  const float* pa0 = x + (size_t)ide[min(row0 + sr,      cnt - 1)] * D_MODEL + sk;
  const float* pa1 = x + (size_t)ide[min(row0 + sr + 64, cnt - 1)] * D_MODEL + sk;
  const float* wge = wgu + (size_t)e * (2 * D_FF) * D_MODEL;
  const float* pg0 = wge + (size_t)(c0 + sr) * D_MODEL + sk;
  const float* pg1 = wge + (size_t)(c0 + sr + 64) * D_MODEL + sk;
  const float* pu0 = wge + (size_t)(D_FF + c0 + sr) * D_MODEL + sk;
  const float* pu1 = wge + (size_t)(D_FF + c0 + sr + 64) * D_MODEL + sk;

  bf16* wA0 = lA  + sr * PITCH + sk;  bf16* wA1 = lA  + (sr + 64) * PITCH + sk;
  bf16* wG0 = lBg + sr * PITCH + sk;  bf16* wG1 = lBg + (sr + 64) * PITCH + sk;
  bf16* wU0 = lBu + sr * PITCH + sk;  bf16* wU1 = lBu + (sr + 64) * PITCH + sk;

  const int wm = wave >> 1;              // wave's 64x64 quadrant
  const int wn = wave & 1;
  const int fr = lane & 15;
  const int fq = lane >> 4;
  const bf16* rA = lA  + (wm * 64 + fr) * PITCH + fq * 8;
  const bf16* rG = lBg + (wn * 64 + fr) * PITCH + fq * 8;
  const bf16* rU = lBu + (wn * 64 + fr) * PITCH + fq * 8;

  f32x4 accg[4][4], accu[4][4];
#pragma unroll
  for (int i = 0; i < 4; ++i)
#pragma unroll
    for (int j = 0; j < 4; ++j)
#pragma unroll
      for (int k = 0; k < 4; ++k) { accg[i][j][k] = 0.f; accu[i][j][k] = 0.f; }

  for (int kt = 0; kt < D_MODEL / 32; ++kt) {
    float4 a00 = *(const float4*)pa0, a01 = *(const float4*)(pa0 + 4);
    float4 a10 = *(const float4*)pa1, a11 = *(const float4*)(pa1 + 4);
    float4 g00 = *(const float4*)pg0, g01 = *(const float4*)(pg0 + 4);
    float4 g10 = *(const float4*)pg1, g11 = *(const float4*)(pg1 + 4);
    float4 u00 = *(const float4*)pu0, u01 = *(const float4*)(pu0 + 4);
    float4 u10 = *(const float4*)pu1, u11 = *(const float4*)(pu1 + 4);
    pa0 += 32; pa1 += 32; pg0 += 32; pg1 += 32; pu0 += 32; pu1 += 32;
    // previous iteration's trailing barrier guarantees LDS free for overwrite
    *(bf16x8*)wA0 = cvt8(a00, a01);  *(bf16x8*)wA1 = cvt8(a10, a11);
    *(bf16x8*)wG0 = cvt8(g00, g01);  *(bf16x8*)wG1 = cvt8(g10, g11);
    *(bf16x8*)wU0 = cvt8(u00, u01);  *(bf16x8*)wU1 = cvt8(u10, u11);
    __syncthreads();   // staging visible
    bf16x8 a[4];
#pragma unroll
    for (int fm = 0; fm < 4; ++fm) a[fm] = *(const bf16x8*)(rA + fm * 16 * PITCH);
#pragma unroll
    for (int fn = 0; fn < 4; ++fn) {
      bf16x8 bg = *(const bf16x8*)(rG + fn * 16 * PITCH);
      bf16x8 bu = *(const bf16x8*)(rU + fn * 16 * PITCH);
#pragma unroll
      for (int fm = 0; fm < 4; ++fm) {
        accg[fm][fn] = mfma16(a[fm], bg, accg[fm][fn]);
        accu[fm][fn] = mfma16(a[fm], bu, accu[fm][fn]);
      }
    }
    __syncthreads();   // LDS reads done before next overwrite
  }

  const int hbase = offsets[e] + row0;
#pragma unroll
  for (int fm = 0; fm < 4; ++fm) {
#pragma unroll
    for (int fn = 0; fn < 4; ++fn) {
#pragma unroll
      for (int i = 0; i < 4; ++i) {
        int m = wm * 64 + fm * 16 + fq * 4 + i;   // C/D: row = quad*4+reg
        if (row0 + m < cnt) {
          float g = accg[fm][fn][i];
          float u = accu[fm][fn][i];
          float h = g * u / (1.f + expf(-u));     // gate * silu(up)
          int col = c0 + wn * 64 + fn * 16 + fr;  // C/D: col = lane&15
          H[(size_t)(hbase + m) * D_FF + col] = (bf16)h;
        }
      }
    }
  }
}

// ===== GEMM2: H(bf16) @ Wd^T(fp32->bf16) ; epilogue: atomicAdd(w * acc) into fp32 out =====
__global__ __launch_bounds__(256, 2) void gemm2_kernel(
    const bf16* __restrict__ H, const float* __restrict__ wd,
    const int* __restrict__ counts, const int* __restrict__ offsets,
    const int* __restrict__ ids, const float* __restrict__ wts,
    float* __restrict__ out)
{
  const int e = blockIdx.z;
  const int cnt = counts[e];
  const int row0 = blockIdx.y * 128;
  if (row0 >= cnt) return;
  const int c0 = blockIdx.x * 128;       // output col tile in [0, 1024)
  const int base = offsets[e];

  __shared__ bf16 lA[128 * 32];          // unpadded: cp16 raw bf16 staging (m97 pattern)
  __shared__ bf16 lB[128 * PITCH];       // padded: cvt staging

  const int tid  = threadIdx.x;
  const int lane = tid & 63;
  const int wave = tid >> 6;

  // A staging (cp16): per wave-issue 16 rows; lane -> (row l4, 16B chunk kb)
  const int l4 = lane >> 2;
  const int kb = (lane & 3) * 8;
  const int ra0 = wave * 16 + l4;
  const int ra1 = (wave + 4) * 16 + l4;
  const int m0 = min(row0 + ra0, cnt - 1);
  const int m1 = min(row0 + ra1, cnt - 1);
  const bf16* srcA0 = H + (size_t)(base + m0) * D_FF + kb;
  const bf16* srcA1 = H + (size_t)(base + m1) * D_FF + kb;
  char* dA0 = (char*)lA + wave * 1024;
  char* dA1 = (char*)lA + (wave + 4) * 1024;

  // B staging (fp32 -> bf16)
  const int sr = tid >> 2;
  const int sk = (tid & 3) * 8;
  const float* wde = wd + (size_t)e * D_MODEL * D_FF;
  const float* pb0 = wde + (size_t)(c0 + sr) * D_FF + sk;
  const float* pb1 = wde + (size_t)(c0 + sr + 64) * D_FF + sk;
  bf16* wB0 = lB + sr * PITCH + sk;
  bf16* wB1 = lB + (sr + 64) * PITCH + sk;

  const int wm = wave >> 1;
  const int wn = wave & 1;
  const int fr = lane & 15;
  const int fq = lane >> 4;
  const bf16* rA = lA + (wm * 64 + fr) * 32 + fq * 8;
  const bf16* rB = lB + (wn * 64 + fr) * PITCH + fq * 8;

  f32x4 acc[4][4];
#pragma unroll
  for (int i = 0; i < 4; ++i)
#pragma unroll
    for (int j = 0; j < 4; ++j)
#pragma unroll
      for (int k = 0; k < 4; ++k) acc[i][j][k] = 0.f;

  for (int kt = 0; kt < D_FF / 32; ++kt) {
    float4 b00 = *(const float4*)pb0, b01 = *(const float4*)(pb0 + 4);
    float4 b10 = *(const float4*)pb1, b11 = *(const float4*)(pb1 + 4);
    cp16(dA0, srcA0); cp16(dA1, srcA1);
    srcA0 += 32; srcA1 += 32; pb0 += 32; pb1 += 32;
    *(bf16x8*)wB0 = cvt8(b00, b01);
    *(bf16x8*)wB1 = cvt8(b10, b11);
    __syncthreads();   // vmcnt+lgkm drained -> tiles ready
    bf16x8 a[4];
#pragma unroll
    for (int fm = 0; fm < 4; ++fm) a[fm] = *(const bf16x8*)(rA + fm * 16 * 32);
#pragma unroll
    for (int fn = 0; fn < 4; ++fn) {
      bf16x8 b = *(const bf16x8*)(rB + fn * 16 * PITCH);
#pragma unroll
      for (int fm = 0; fm < 4; ++fm) acc[fm][fn] = mfma16(a[fm], b, acc[fm][fn]);
    }
    __syncthreads();
  }

  const int* ide = ids + e * N_TOK;
  const float* wte = wts + e * N_TOK;
#pragma unroll
  for (int fm = 0; fm < 4; ++fm) {
#pragma unroll
    for (int i = 0; i < 4; ++i) {
      int m = wm * 64 + fm * 16 + fq * 4 + i;
      if (row0 + m < cnt) {
        int   tok = ide[row0 + m];
        float w   = wte[row0 + m];
        float* orow = out + (size_t)tok * D_MODEL;
#pragma unroll
        for (int fn = 0; fn < 4; ++fn) {
          int col = c0 + wn * 64 + fn * 16 + fr;
          atomicAdd(orow + col, w * acc[fm][fn][i]);
        }
      }
    }
  }
}

// =========================================================================================
extern "C" void kernel_launch(void* const* d_in, const int* in_sizes, int n_in,
                              void* d_out, int out_size, void* d_ws, size_t ws_size,
                              hipStream_t stream) {
  const float* x   = (const float*)d_in[0];
  const float* wr  = (const float*)d_in[1];
  const float* wgu = (const float*)d_in[2];
  const float* wd  = (const float*)d_in[3];
  float* out = (float*)d_out;

  char* ws = (char*)d_ws;
  // workspace layout — total ~32.5 MB
  int*   counts  = (int*)ws;                          // 32 B
  int*   offsets = (int*)(ws + 64);                   // 32 B
  int*   ids     = (int*)(ws + 4096);                 // 8*4096*4 = 128 KB
  float* wts     = (float*)(ws + 4096 + 131072);      // 128 KB
  bf16*  H       = (bf16*)(ws + 524288);              // 8192*2048*2 = 32 MB

  hipMemsetAsync(counts, 0, 64, stream);
  hipMemsetAsync(out, 0, (size_t)N_TOK * D_MODEL * sizeof(float), stream);
  router_kernel<<<N_TOK / 4, 256, 0, stream>>>(x, wr, counts, ids, wts);
  offsets_kernel<<<1, 64, 0, stream>>>(counts, offsets);
  gemm1_kernel<<<dim3(D_FF / 128, N_TOK / 128, N_EXP), 256, 0, stream>>>(
      x, wgu, counts, offsets, ids, H);
  gemm2_kernel<<<dim3(D_MODEL / 128, N_TOK / 128, N_EXP), 256, 0, stream>>>(
      H, wd, counts, offsets, ids, wts, out);
}

// Round 4
// 582.340 us; speedup vs baseline: 1.0619x; 1.0619x over previous
//
#include <hip/hip_runtime.h>
#include <cstdint>

// ---- problem constants (MoEFeedForward: N=4096, D=1024, F=2048, E=8, top-2) ----
#define N_TOK 4096
#define D_MODEL 1024
#define D_FF 2048
#define N_EXP 8
#define PITCH 40   // padded LDS pitch (bf16 elems) for the fp32-cvt fallback path

typedef __bf16 bf16;
typedef __bf16 bf16x8 __attribute__((ext_vector_type(8)));
typedef __bf16 bf16x4 __attribute__((ext_vector_type(4)));
typedef float f32x4 __attribute__((ext_vector_type(4)));

typedef __attribute__((address_space(1))) void v1_t;
typedef __attribute__((address_space(3))) void v3_t;

// async global->LDS raw copy, 16B/lane; dest = wave-uniform base + lane*16
__device__ __forceinline__ void cp16(void* lds, const void* g) {
  __builtin_amdgcn_global_load_lds((v1_t*)g, (v3_t*)lds, 16, 0, 0);
}

__device__ __forceinline__ f32x4 mfma16(bf16x8 a, bf16x8 b, f32x4 c) {
  return __builtin_amdgcn_mfma_f32_16x16x32_bf16(a, b, c, 0, 0, 0);
}

__device__ __forceinline__ bf16x8 cvt8(float4 a, float4 b) {
  bf16x8 v;
  v[0] = (bf16)a.x; v[1] = (bf16)a.y; v[2] = (bf16)a.z; v[3] = (bf16)a.w;
  v[4] = (bf16)b.x; v[5] = (bf16)b.y; v[6] = (bf16)b.z; v[7] = (bf16)b.w;
  return v;
}

// ======================= router: fp32 logits -> softmax -> top2 -> expert lists ==============
__global__ __launch_bounds__(256) void router_kernel(
    const float* __restrict__ x, const float* __restrict__ wr,
    int* __restrict__ counts, int* __restrict__ ids, float* __restrict__ wts)
{
  const int token = blockIdx.x * 4 + (threadIdx.x >> 6);
  const int lane  = threadIdx.x & 63;

  const float4* xrow = (const float4*)(x + (size_t)token * D_MODEL + lane * 16);
  float4 x0 = xrow[0], x1 = xrow[1], x2 = xrow[2], x3 = xrow[3];

  float logit[N_EXP];
#pragma unroll
  for (int e = 0; e < N_EXP; ++e) {
    const float4* wrow = (const float4*)(wr + e * D_MODEL + lane * 16);
    float4 w0 = wrow[0], w1 = wrow[1], w2 = wrow[2], w3 = wrow[3];
    float s = x0.x*w0.x + x0.y*w0.y + x0.z*w0.z + x0.w*w0.w
            + x1.x*w1.x + x1.y*w1.y + x1.z*w1.z + x1.w*w1.w
            + x2.x*w2.x + x2.y*w2.y + x2.z*w2.z + x2.w*w2.w
            + x3.x*w3.x + x3.y*w3.y + x3.z*w3.z + x3.w*w3.w;
#pragma unroll
    for (int m = 32; m >= 1; m >>= 1) s += __shfl_xor(s, m);
    logit[e] = fminf(fmaxf(s, -1e4f), 1e4f);
  }

  if (lane == 0) {
    float mx = logit[0];
#pragma unroll
    for (int e = 1; e < N_EXP; ++e) mx = fmaxf(mx, logit[e]);
    float ex[N_EXP], sum = 0.f;
#pragma unroll
    for (int e = 0; e < N_EXP; ++e) { ex[e] = expf(logit[e] - mx); sum += ex[e]; }
    float p[N_EXP];
#pragma unroll
    for (int e = 0; e < N_EXP; ++e)
      p[e] = fminf(fmaxf(ex[e] / (sum + 1e-8f), 1e-8f), 1.0f);
    int e0 = 0;
#pragma unroll
    for (int e = 1; e < N_EXP; ++e) if (p[e] > p[e0]) e0 = e;
    int e1 = (e0 == 0) ? 1 : 0;
#pragma unroll
    for (int e = 0; e < N_EXP; ++e) if (e != e0 && p[e] > p[e1]) e1 = e;
    float p0 = p[e0], p1 = p[e1];
    float inv = 1.f / (p0 + p1 + 1e-8f);
    p0 *= inv; p1 *= inv;
    int l0 = atomicAdd(&counts[e0], 1);
    int l1 = atomicAdd(&counts[e1], 1);
    ids[e0 * N_TOK + l0] = token; wts[e0 * N_TOK + l0] = p0;
    ids[e1 * N_TOK + l1] = token; wts[e1 * N_TOK + l1] = p1;
  }
}

__global__ void offsets_kernel(const int* __restrict__ counts, int* __restrict__ offsets) {
  if (threadIdx.x == 0) {
    int r = 0;
#pragma unroll
    for (int e = 0; e < N_EXP; ++e) { offsets[e] = r; r += counts[e]; }
  }
}

// ======================= fp32 -> bf16 bulk convert (grid-stride, float4 granularity) ==========
__global__ __launch_bounds__(256) void cvt_kernel(
    const float* __restrict__ src, bf16* __restrict__ dst, int n4)
{
  int i = blockIdx.x * 256 + threadIdx.x;
  const int stride = gridDim.x * 256;
  for (; i < n4; i += stride) {
    float4 v = ((const float4*)src)[i];
    bf16x4 r;
    r[0] = (bf16)v.x; r[1] = (bf16)v.y; r[2] = (bf16)v.z; r[3] = (bf16)v.w;
    ((bf16x4*)dst)[i] = r;
  }
}

// ===================== FAST PATH: all-bf16 m97-pattern GEMMs (cp16 staging) ==================

// GEMM1: gathered xb @ Wgu_b^T -> SwiGLU -> H (bf16). 128x128 tile, dual B stream.
__global__ __launch_bounds__(256, 2) void gemm1_fast(
    const bf16* __restrict__ xb, const bf16* __restrict__ wgu,
    const int* __restrict__ counts, const int* __restrict__ offsets,
    const int* __restrict__ ids, bf16* __restrict__ H)
{
  const int e = blockIdx.z;
  const int cnt = counts[e];
  const int row0 = blockIdx.y * 128;
  if (row0 >= cnt) return;
  const int c0 = blockIdx.x * 128;

  __shared__ bf16 lA[128 * 32];
  __shared__ bf16 lBg[128 * 32];
  __shared__ bf16 lBu[128 * 32];

  const int tid  = threadIdx.x;
  const int lane = tid & 63;
  const int wave = tid >> 6;
  const int l4 = lane >> 2;
  const int kb = (lane & 3) * 8;

  const int ra0 = wave * 16 + l4;
  const int ra1 = (wave + 4) * 16 + l4;

  const int* ide = ids + e * N_TOK;
  const int m0 = min(row0 + ra0, cnt - 1);
  const int m1 = min(row0 + ra1, cnt - 1);
  const bf16* srcA0 = xb + (size_t)ide[m0] * D_MODEL + kb;
  const bf16* srcA1 = xb + (size_t)ide[m1] * D_MODEL + kb;
  const bf16* wge = wgu + (size_t)e * (2 * D_FF) * D_MODEL;
  const bf16* srcG0 = wge + (size_t)(c0 + ra0) * D_MODEL + kb;
  const bf16* srcG1 = wge + (size_t)(c0 + ra1) * D_MODEL + kb;
  const bf16* srcU0 = wge + (size_t)(D_FF + c0 + ra0) * D_MODEL + kb;
  const bf16* srcU1 = wge + (size_t)(D_FF + c0 + ra1) * D_MODEL + kb;

  char* dA0 = (char*)lA  + wave * 1024;
  char* dA1 = (char*)lA  + (wave + 4) * 1024;
  char* dG0 = (char*)lBg + wave * 1024;
  char* dG1 = (char*)lBg + (wave + 4) * 1024;
  char* dU0 = (char*)lBu + wave * 1024;
  char* dU1 = (char*)lBu + (wave + 4) * 1024;

  const int wm = wave >> 1;
  const int wn = wave & 1;
  const int fr = lane & 15;
  const int fq = lane >> 4;
  const bf16* pA  = lA  + (wm * 64 + fr) * 32 + fq * 8;
  const bf16* pBg = lBg + (wn * 64 + fr) * 32 + fq * 8;
  const bf16* pBu = lBu + (wn * 64 + fr) * 32 + fq * 8;

  f32x4 accg[4][4], accu[4][4];
#pragma unroll
  for (int i = 0; i < 4; ++i)
#pragma unroll
    for (int j = 0; j < 4; ++j)
#pragma unroll
      for (int k = 0; k < 4; ++k) { accg[i][j][k] = 0.f; accu[i][j][k] = 0.f; }

  for (int kt = 0; kt < D_MODEL / 32; ++kt) {
    cp16(dA0, srcA0); cp16(dA1, srcA1);
    cp16(dG0, srcG0); cp16(dG1, srcG1);
    cp16(dU0, srcU0); cp16(dU1, srcU1);
    srcA0 += 32; srcA1 += 32; srcG0 += 32; srcG1 += 32; srcU0 += 32; srcU1 += 32;
    __syncthreads();
    bf16x8 a[4];
#pragma unroll
    for (int fm = 0; fm < 4; ++fm) a[fm] = *(const bf16x8*)(pA + fm * 16 * 32);
#pragma unroll
    for (int fn = 0; fn < 4; ++fn) {
      bf16x8 bg = *(const bf16x8*)(pBg + fn * 16 * 32);
      bf16x8 bu = *(const bf16x8*)(pBu + fn * 16 * 32);
#pragma unroll
      for (int fm = 0; fm < 4; ++fm) {
        accg[fm][fn] = mfma16(a[fm], bg, accg[fm][fn]);
        accu[fm][fn] = mfma16(a[fm], bu, accu[fm][fn]);
      }
    }
    __syncthreads();
  }

  const int hbase = offsets[e] + row0;
#pragma unroll
  for (int fm = 0; fm < 4; ++fm) {
#pragma unroll
    for (int fn = 0; fn < 4; ++fn) {
#pragma unroll
      for (int i = 0; i < 4; ++i) {
        int m = wm * 64 + fm * 16 + fq * 4 + i;
        if (row0 + m < cnt) {
          float g = accg[fm][fn][i];
          float u = accu[fm][fn][i];
          float h = g * u / (1.f + expf(-u));
          int col = c0 + wn * 64 + fn * 16 + fr;
          H[(size_t)(hbase + m) * D_FF + col] = (bf16)h;
        }
      }
    }
  }
}

// GEMM2: H(bf16) @ Wd_b^T -> atomicAdd(w * acc) into fp32 out. 128x128 tile.
__global__ __launch_bounds__(256, 2) void gemm2_fast(
    const bf16* __restrict__ H, const bf16* __restrict__ wdb,
    const int* __restrict__ counts, const int* __restrict__ offsets,
    const int* __restrict__ ids, const float* __restrict__ wts,
    float* __restrict__ out)
{
  const int e = blockIdx.z;
  const int cnt = counts[e];
  const int row0 = blockIdx.y * 128;
  if (row0 >= cnt) return;
  const int c0 = blockIdx.x * 128;
  const int base = offsets[e];

  __shared__ bf16 lA[128 * 32];
  __shared__ bf16 lB[128 * 32];

  const int tid  = threadIdx.x;
  const int lane = tid & 63;
  const int wave = tid >> 6;
  const int l4 = lane >> 2;
  const int kb = (lane & 3) * 8;

  const int ra0 = wave * 16 + l4;
  const int ra1 = (wave + 4) * 16 + l4;
  const int m0 = min(row0 + ra0, cnt - 1);
  const int m1 = min(row0 + ra1, cnt - 1);
  const bf16* srcA0 = H + (size_t)(base + m0) * D_FF + kb;
  const bf16* srcA1 = H + (size_t)(base + m1) * D_FF + kb;
  const bf16* wde = wdb + (size_t)e * D_MODEL * D_FF;
  const bf16* srcB0 = wde + (size_t)(c0 + ra0) * D_FF + kb;
  const bf16* srcB1 = wde + (size_t)(c0 + ra1) * D_FF + kb;

  char* dA0 = (char*)lA + wave * 1024;
  char* dA1 = (char*)lA + (wave + 4) * 1024;
  char* dB0 = (char*)lB + wave * 1024;
  char* dB1 = (char*)lB + (wave + 4) * 1024;

  const int wm = wave >> 1;
  const int wn = wave & 1;
  const int fr = lane & 15;
  const int fq = lane >> 4;
  const bf16* pA = lA + (wm * 64 + fr) * 32 + fq * 8;
  const bf16* pB = lB + (wn * 64 + fr) * 32 + fq * 8;

  f32x4 acc[4][4];
#pragma unroll
  for (int i = 0; i < 4; ++i)
#pragma unroll
    for (int j = 0; j < 4; ++j)
#pragma unroll
      for (int k = 0; k < 4; ++k) acc[i][j][k] = 0.f;

  for (int kt = 0; kt < D_FF / 32; ++kt) {
    cp16(dA0, srcA0); cp16(dA1, srcA1);
    cp16(dB0, srcB0); cp16(dB1, srcB1);
    srcA0 += 32; srcA1 += 32; srcB0 += 32; srcB1 += 32;
    __syncthreads();
    bf16x8 a[4];
#pragma unroll
    for (int fm = 0; fm < 4; ++fm) a[fm] = *(const bf16x8*)(pA + fm * 16 * 32);
#pragma unroll
    for (int fn = 0; fn < 4; ++fn) {
      bf16x8 b = *(const bf16x8*)(pB + fn * 16 * 32);
#pragma unroll
      for (int fm = 0; fm < 4; ++fm) acc[fm][fn] = mfma16(a[fm], b, acc[fm][fn]);
    }
    __syncthreads();
  }

  const int* ide = ids + e * N_TOK;
  const float* wte = wts + e * N_TOK;
#pragma unroll
  for (int fm = 0; fm < 4; ++fm) {
#pragma unroll
    for (int i = 0; i < 4; ++i) {
      int m = wm * 64 + fm * 16 + fq * 4 + i;
      if (row0 + m < cnt) {
        int   tok = ide[row0 + m];
        float w   = wte[row0 + m];
        float* orow = out + (size_t)tok * D_MODEL;
#pragma unroll
        for (int fn = 0; fn < 4; ++fn) {
          int col = c0 + wn * 64 + fn * 16 + fr;
          atomicAdd(orow + col, w * acc[fm][fn][i]);
        }
      }
    }
  }
}

// ===================== FALLBACK PATH (round-3 verified kernels, fp32 operands) ================

__global__ __launch_bounds__(256, 2) void gemm1_kernel(
    const float* __restrict__ x, const float* __restrict__ wgu,
    const int* __restrict__ counts, const int* __restrict__ offsets,
    const int* __restrict__ ids, bf16* __restrict__ H)
{
  const int e = blockIdx.z;
  const int cnt = counts[e];
  const int row0 = blockIdx.y * 128;
  if (row0 >= cnt) return;
  const int c0 = blockIdx.x * 128;

  __shared__ bf16 lA [128 * PITCH];
  __shared__ bf16 lBg[128 * PITCH];
  __shared__ bf16 lBu[128 * PITCH];

  const int tid  = threadIdx.x;
  const int lane = tid & 63;
  const int wave = tid >> 6;
  const int sr = tid >> 2;
  const int sk = (tid & 3) * 8;

  const int* ide = ids + e * N_TOK;
  const float* pa0 = x + (size_t)ide[min(row0 + sr,      cnt - 1)] * D_MODEL + sk;
  const float* pa1 = x + (size_t)ide[min(row0 + sr + 64, cnt - 1)] * D_MODEL + sk;
  const float* wge = wgu + (size_t)e * (2 * D_FF) * D_MODEL;
  const float* pg0 = wge + (size_t)(c0 + sr) * D_MODEL + sk;
  const float* pg1 = wge + (size_t)(c0 + sr + 64) * D_MODEL + sk;
  const float* pu0 = wge + (size_t)(D_FF + c0 + sr) * D_MODEL + sk;
  const float* pu1 = wge + (size_t)(D_FF + c0 + sr + 64) * D_MODEL + sk;

  bf16* wA0 = lA  + sr * PITCH + sk;  bf16* wA1 = lA  + (sr + 64) * PITCH + sk;
  bf16* wG0 = lBg + sr * PITCH + sk;  bf16* wG1 = lBg + (sr + 64) * PITCH + sk;
  bf16* wU0 = lBu + sr * PITCH + sk;  bf16* wU1 = lBu + (sr + 64) * PITCH + sk;

  const int wm = wave >> 1;
  const int wn = wave & 1;
  const int fr = lane & 15;
  const int fq = lane >> 4;
  const bf16* rA = lA  + (wm * 64 + fr) * PITCH + fq * 8;
  const bf16* rG = lBg + (wn * 64 + fr) * PITCH + fq * 8;
  const bf16* rU = lBu + (wn * 64 + fr) * PITCH + fq * 8;

  f32x4 accg[4][4], accu[4][4];
#pragma unroll
  for (int i = 0; i < 4; ++i)
#pragma unroll
    for (int j = 0; j < 4; ++j)
#pragma unroll
      for (int k = 0; k < 4; ++k) { accg[i][j][k] = 0.f; accu[i][j][k] = 0.f; }

  for (int kt = 0; kt < D_MODEL / 32; ++kt) {
    float4 a00 = *(const float4*)pa0, a01 = *(const float4*)(pa0 + 4);
    float4 a10 = *(const float4*)pa1, a11 = *(const float4*)(pa1 + 4);
    float4 g00 = *(const float4*)pg0, g01 = *(const float4*)(pg0 + 4);
    float4 g10 = *(const float4*)pg1, g11 = *(const float4*)(pg1 + 4);
    float4 u00 = *(const float4*)pu0, u01 = *(const float4*)(pu0 + 4);
    float4 u10 = *(const float4*)pu1, u11 = *(const float4*)(pu1 + 4);
    pa0 += 32; pa1 += 32; pg0 += 32; pg1 += 32; pu0 += 32; pu1 += 32;
    *(bf16x8*)wA0 = cvt8(a00, a01);  *(bf16x8*)wA1 = cvt8(a10, a11);
    *(bf16x8*)wG0 = cvt8(g00, g01);  *(bf16x8*)wG1 = cvt8(g10, g11);
    *(bf16x8*)wU0 = cvt8(u00, u01);  *(bf16x8*)wU1 = cvt8(u10, u11);
    __syncthreads();
    bf16x8 a[4];
#pragma unroll
    for (int fm = 0; fm < 4; ++fm) a[fm] = *(const bf16x8*)(rA + fm * 16 * PITCH);
#pragma unroll
    for (int fn = 0; fn < 4; ++fn) {
      bf16x8 bg = *(const bf16x8*)(rG + fn * 16 * PITCH);
      bf16x8 bu = *(const bf16x8*)(rU + fn * 16 * PITCH);
#pragma unroll
      for (int fm = 0; fm < 4; ++fm) {
        accg[fm][fn] = mfma16(a[fm], bg, accg[fm][fn]);
        accu[fm][fn] = mfma16(a[fm], bu, accu[fm][fn]);
      }
    }
    __syncthreads();
  }

  const int hbase = offsets[e] + row0;
#pragma unroll
  for (int fm = 0; fm < 4; ++fm) {
#pragma unroll
    for (int fn = 0; fn < 4; ++fn) {
#pragma unroll
      for (int i = 0; i < 4; ++i) {
        int m = wm * 64 + fm * 16 + fq * 4 + i;
        if (row0 + m < cnt) {
          float g = accg[fm][fn][i];
          float u = accu[fm][fn][i];
          float h = g * u / (1.f + expf(-u));
          int col = c0 + wn * 64 + fn * 16 + fr;
          H[(size_t)(hbase + m) * D_FF + col] = (bf16)h;
        }
      }
    }
  }
}

__global__ __launch_bounds__(256, 2) void gemm2_kernel(
    const bf16* __restrict__ H, const float* __restrict__ wd,
    const int* __restrict__ counts, const int* __restrict__ offsets,
    const int* __restrict__ ids, const float* __restrict__ wts,
    float* __restrict__ out)
{
  const int e = blockIdx.z;
  const int cnt = counts[e];
  const int row0 = blockIdx.y * 128;
  if (row0 >= cnt) return;
  const int c0 = blockIdx.x * 128;
  const int base = offsets[e];

  __shared__ bf16 lA[128 * 32];
  __shared__ bf16 lB[128 * PITCH];

  const int tid  = threadIdx.x;
  const int lane = tid & 63;
  const int wave = tid >> 6;
  const int l4 = lane >> 2;
  const int kb = (lane & 3) * 8;
  const int ra0 = wave * 16 + l4;
  const int ra1 = (wave + 4) * 16 + l4;
  const int m0 = min(row0 + ra0, cnt - 1);
  const int m1 = min(row0 + ra1, cnt - 1);
  const bf16* srcA0 = H + (size_t)(base + m0) * D_FF + kb;
  const bf16* srcA1 = H + (size_t)(base + m1) * D_FF + kb;
  char* dA0 = (char*)lA + wave * 1024;
  char* dA1 = (char*)lA + (wave + 4) * 1024;

  const int sr = tid >> 2;
  const int sk = (tid & 3) * 8;
  const float* wde = wd + (size_t)e * D_MODEL * D_FF;
  const float* pb0 = wde + (size_t)(c0 + sr) * D_FF + sk;
  const float* pb1 = wde + (size_t)(c0 + sr + 64) * D_FF + sk;
  bf16* wB0 = lB + sr * PITCH + sk;
  bf16* wB1 = lB + (sr + 64) * PITCH + sk;

  const int wm = wave >> 1;
  const int wn = wave & 1;
  const int fr = lane & 15;
  const int fq = lane >> 4;
  const bf16* rA = lA + (wm * 64 + fr) * 32 + fq * 8;
  const bf16* rB = lB + (wn * 64 + fr) * PITCH + fq * 8;

  f32x4 acc[4][4];
#pragma unroll
  for (int i = 0; i < 4; ++i)
#pragma unroll
    for (int j = 0; j < 4; ++j)
#pragma unroll
      for (int k = 0; k < 4; ++k) acc[i][j][k] = 0.f;

  for (int kt = 0; kt < D_FF / 32; ++kt) {
    float4 b00 = *(const float4*)pb0, b01 = *(const float4*)(pb0 + 4);
    float4 b10 = *(const float4*)pb1, b11 = *(const float4*)(pb1 + 4);
    cp16(dA0, srcA0); cp16(dA1, srcA1);
    srcA0 += 32; srcA1 += 32; pb0 += 32; pb1 += 32;
    *(bf16x8*)wB0 = cvt8(b00, b01);
    *(bf16x8*)wB1 = cvt8(b10, b11);
    __syncthreads();
    bf16x8 a[4];
#pragma unroll
    for (int fm = 0; fm < 4; ++fm) a[fm] = *(const bf16x8*)(rA + fm * 16 * 32);
#pragma unroll
    for (int fn = 0; fn < 4; ++fn) {
      bf16x8 b = *(const bf16x8*)(rB + fn * 16 * PITCH);
#pragma unroll
      for (int fm = 0; fm < 4; ++fm) acc[fm][fn] = mfma16(a[fm], b, acc[fm][fn]);
    }
    __syncthreads();
  }

  const int* ide = ids + e * N_TOK;
  const float* wte = wts + e * N_TOK;
#pragma unroll
  for (int fm = 0; fm < 4; ++fm) {
#pragma unroll
    for (int i = 0; i < 4; ++i) {
      int m = wm * 64 + fm * 16 + fq * 4 + i;
      if (row0 + m < cnt) {
        int   tok = ide[row0 + m];
        float w   = wte[row0 + m];
        float* orow = out + (size_t)tok * D_MODEL;
#pragma unroll
        for (int fn = 0; fn < 4; ++fn) {
          int col = c0 + wn * 64 + fn * 16 + fr;
          atomicAdd(orow + col, w * acc[fm][fn][i]);
        }
      }
    }
  }
}

// =========================================================================================
extern "C" void kernel_launch(void* const* d_in, const int* in_sizes, int n_in,
                              void* d_out, int out_size, void* d_ws, size_t ws_size,
                              hipStream_t stream) {
  const float* x   = (const float*)d_in[0];
  const float* wr  = (const float*)d_in[1];
  const float* wgu = (const float*)d_in[2];
  const float* wd  = (const float*)d_in[3];
  float* out = (float*)d_out;

  char* ws = (char*)d_ws;
  int*   counts  = (int*)ws;
  int*   offsets = (int*)(ws + 64);
  int*   ids     = (int*)(ws + 4096);
  float* wts     = (float*)(ws + 4096 + 131072);

  // fast-path workspace layout
  const size_t XB_OFF  = 524288;                 // 8 MB  (x bf16)
  const size_t H_OFF   = XB_OFF + 8388608;       // 32 MB (H bf16)
  const size_t WGU_OFF = H_OFF + 33554432;       // 64 MB (wgu bf16)
  const size_t WD_OFF  = WGU_OFF + 67108864;     // 32 MB (wd bf16)
  const size_t NEED    = WD_OFF + 33554432;      // 136.5 MB total

  hipMemsetAsync(counts, 0, 64, stream);
  hipMemsetAsync(out, 0, (size_t)N_TOK * D_MODEL * sizeof(float), stream);
  router_kernel<<<N_TOK / 4, 256, 0, stream>>>(x, wr, counts, ids, wts);
  offsets_kernel<<<1, 64, 0, stream>>>(counts, offsets);

  if (ws_size >= NEED) {
    bf16* xb   = (bf16*)(ws + XB_OFF);
    bf16* H    = (bf16*)(ws + H_OFF);
    bf16* wgub = (bf16*)(ws + WGU_OFF);
    bf16* wdb  = (bf16*)(ws + WD_OFF);
    cvt_kernel<<<1024, 256, 0, stream>>>(x,   xb,   (N_TOK * D_MODEL) / 4);
    cvt_kernel<<<2048, 256, 0, stream>>>(wgu, wgub, (N_EXP * 2 * D_FF * D_MODEL) / 4);
    cvt_kernel<<<2048, 256, 0, stream>>>(wd,  wdb,  (N_EXP * D_MODEL * D_FF) / 4);
    gemm1_fast<<<dim3(D_FF / 128, N_TOK / 128, N_EXP), 256, 0, stream>>>(
        xb, wgub, counts, offsets, ids, H);
    gemm2_fast<<<dim3(D_MODEL / 128, N_TOK / 128, N_EXP), 256, 0, stream>>>(
        H, wdb, counts, offsets, ids, wts, out);
  } else {
    bf16* H = (bf16*)(ws + 524288);   // fallback: only H needed (32 MB @ 0.5 MB)
    gemm1_kernel<<<dim3(D_FF / 128, N_TOK / 128, N_EXP), 256, 0, stream>>>(
        x, wgu, counts, offsets, ids, H);
    gemm2_kernel<<<dim3(D_MODEL / 128, N_TOK / 128, N_EXP), 256, 0, stream>>>(
        H, wd, counts, offsets, ids, wts, out);
  }
}

// Round 5
// 489.950 us; speedup vs baseline: 1.2622x; 1.1886x over previous
//
#include <hip/hip_runtime.h>
#include <cstdint>

// ---- problem constants (MoEFeedForward: N=4096, D=1024, F=2048, E=8, top-2) ----
#define N_TOK 4096
#define D_MODEL 1024
#define D_FF 2048
#define D_GU 4096          // 2*D_FF: gate_up col space; also GU row pitch
#define N_EXP 8

typedef __bf16 bf16;
typedef __bf16 bf16x8 __attribute__((ext_vector_type(8)));
typedef float f32x4 __attribute__((ext_vector_type(4)));

typedef __attribute__((address_space(1))) void v1_t;
typedef __attribute__((address_space(3))) void v3_t;

// async global->LDS raw copy, 16B/lane; dest = wave-uniform base + lane*16
__device__ __forceinline__ void cp16(void* lds, const void* g) {
  __builtin_amdgcn_global_load_lds((v1_t*)g, (v3_t*)lds, 16, 0, 0);
}

__device__ __forceinline__ f32x4 mfma16(bf16x8 a, bf16x8 b, f32x4 c) {
  return __builtin_amdgcn_mfma_f32_16x16x32_bf16(a, b, c, 0, 0, 0);
}

__device__ __forceinline__ bf16x8 cvt8(float4 a, float4 b) {
  bf16x8 v;
  v[0] = (bf16)a.x; v[1] = (bf16)a.y; v[2] = (bf16)a.z; v[3] = (bf16)a.w;
  v[4] = (bf16)b.x; v[5] = (bf16)b.y; v[6] = (bf16)b.z; v[7] = (bf16)b.w;
  return v;
}

// ======== router: logits->softmax->top2->expert lists; fuses x fp32->bf16 conversion ========
// 32 tokens per block (wave-per-token x 8 iters); LDS-aggregated count atomics.
__global__ __launch_bounds__(256) void router_kernel(
    const float* __restrict__ x, const float* __restrict__ wr,
    int* __restrict__ counts, int* __restrict__ ids, float* __restrict__ wts,
    bf16* __restrict__ xb)
{
  __shared__ int lcnt[N_EXP];
  __shared__ int gbase[N_EXP];
  __shared__ int s_e0[32], s_l0[32], s_e1[32], s_l1[32];
  __shared__ float s_p0[32], s_p1[32];

  const int tid  = threadIdx.x;
  const int wave = tid >> 6;
  const int lane = tid & 63;
  if (tid < N_EXP) lcnt[tid] = 0;
  __syncthreads();

  for (int it = 0; it < 8; ++it) {
    const int li = it * 4 + wave;                 // local token 0..31
    const int token = blockIdx.x * 32 + li;

    const float4* xrow = (const float4*)(x + (size_t)token * D_MODEL + lane * 16);
    float4 x0 = xrow[0], x1 = xrow[1], x2 = xrow[2], x3 = xrow[3];

    // side-product: bf16 copy of x (coalesced 16B stores)
    bf16* xd = xb + (size_t)token * D_MODEL + lane * 16;
    *(bf16x8*)xd       = cvt8(x0, x1);
    *(bf16x8*)(xd + 8) = cvt8(x2, x3);

    float logit[N_EXP];
#pragma unroll
    for (int e = 0; e < N_EXP; ++e) {
      const float4* wrow = (const float4*)(wr + e * D_MODEL + lane * 16);
      float4 w0 = wrow[0], w1 = wrow[1], w2 = wrow[2], w3 = wrow[3];
      float s = x0.x*w0.x + x0.y*w0.y + x0.z*w0.z + x0.w*w0.w
              + x1.x*w1.x + x1.y*w1.y + x1.z*w1.z + x1.w*w1.w
              + x2.x*w2.x + x2.y*w2.y + x2.z*w2.z + x2.w*w2.w
              + x3.x*w3.x + x3.y*w3.y + x3.z*w3.z + x3.w*w3.w;
#pragma unroll
      for (int m = 32; m >= 1; m >>= 1) s += __shfl_xor(s, m);
      logit[e] = fminf(fmaxf(s, -1e4f), 1e4f);    // reference CLAMP
    }

    if (lane == 0) {
      float mx = logit[0];
#pragma unroll
      for (int e = 1; e < N_EXP; ++e) mx = fmaxf(mx, logit[e]);
      float ex[N_EXP], sum = 0.f;
#pragma unroll
      for (int e = 0; e < N_EXP; ++e) { ex[e] = expf(logit[e] - mx); sum += ex[e]; }
      float p[N_EXP];
#pragma unroll
      for (int e = 0; e < N_EXP; ++e)
        p[e] = fminf(fmaxf(ex[e] / (sum + 1e-8f), 1e-8f), 1.0f);
      int e0 = 0;
#pragma unroll
      for (int e = 1; e < N_EXP; ++e) if (p[e] > p[e0]) e0 = e;
      int e1 = (e0 == 0) ? 1 : 0;
#pragma unroll
      for (int e = 0; e < N_EXP; ++e) if (e != e0 && p[e] > p[e1]) e1 = e;
      float p0 = p[e0], p1 = p[e1];
      float inv = 1.f / (p0 + p1 + 1e-8f);
      s_e0[li] = e0; s_l0[li] = atomicAdd(&lcnt[e0], 1); s_p0[li] = p0 * inv;
      s_e1[li] = e1; s_l1[li] = atomicAdd(&lcnt[e1], 1); s_p1[li] = p1 * inv;
    }
  }
  __syncthreads();
  if (tid < N_EXP) gbase[tid] = atomicAdd(&counts[tid], lcnt[tid]);
  __syncthreads();
  if (tid < 32) {
    const int token = blockIdx.x * 32 + tid;
    int e0 = s_e0[tid], e1 = s_e1[tid];
    int a = gbase[e0] + s_l0[tid];
    int b = gbase[e1] + s_l1[tid];
    ids[e0 * N_TOK + a] = token; wts[e0 * N_TOK + a] = s_p0[tid];
    ids[e1 * N_TOK + b] = token; wts[e1 * N_TOK + b] = s_p1[tid];
  }
}

__global__ void offsets_kernel(const int* __restrict__ counts, int* __restrict__ offsets) {
  if (threadIdx.x == 0) {
    int r = 0;
#pragma unroll
    for (int e = 0; e < N_EXP; ++e) { offsets[e] = r; r += counts[e]; }
  }
}

// ============ fp32 -> bf16 bulk convert: 32B load / 16B store per thread ============
__global__ __launch_bounds__(256) void cvt_kernel(
    const float* __restrict__ src, bf16* __restrict__ dst, int n8)
{
  int i = blockIdx.x * 256 + threadIdx.x;
  const int stride = gridDim.x * 256;
  for (; i < n8; i += stride) {
    const float4* s = (const float4*)src + 2 * (size_t)i;
    ((bf16x8*)dst)[i] = cvt8(s[0], s[1]);
  }
}

// ====== GEMM1a: gathered xb @ Wgu_b^T -> GU bf16 (compacted rows, pitch 4096) ======
// pure m97 pattern: 128x128 tile, BK=32, single 64-AGPR accumulator
__global__ __launch_bounds__(256, 2) void gemm1a_kernel(
    const bf16* __restrict__ xb, const bf16* __restrict__ wgu,
    const int* __restrict__ counts, const int* __restrict__ offsets,
    const int* __restrict__ ids, bf16* __restrict__ GU)
{
  const int e = blockIdx.z;
  const int cnt = counts[e];
  const int row0 = blockIdx.y * 128;
  if (row0 >= cnt) return;
  const int c0 = blockIdx.x * 128;              // gate_up col tile in [0, 4096)

  __shared__ bf16 lA[128 * 32];
  __shared__ bf16 lB[128 * 32];

  const int tid  = threadIdx.x;
  const int lane = tid & 63;
  const int wave = tid >> 6;
  const int l4 = lane >> 2;
  const int kb = (lane & 3) * 8;

  const int ra0 = wave * 16 + l4;
  const int ra1 = (wave + 4) * 16 + l4;

  const int* ide = ids + e * N_TOK;
  const int m0 = min(row0 + ra0, cnt - 1);
  const int m1 = min(row0 + ra1, cnt - 1);
  const bf16* srcA0 = xb + (size_t)ide[m0] * D_MODEL + kb;
  const bf16* srcA1 = xb + (size_t)ide[m1] * D_MODEL + kb;
  const bf16* wge = wgu + (size_t)e * D_GU * D_MODEL;
  const bf16* srcB0 = wge + (size_t)(c0 + ra0) * D_MODEL + kb;
  const bf16* srcB1 = wge + (size_t)(c0 + ra1) * D_MODEL + kb;

  char* dA0 = (char*)lA + wave * 1024;
  char* dA1 = (char*)lA + (wave + 4) * 1024;
  char* dB0 = (char*)lB + wave * 1024;
  char* dB1 = (char*)lB + (wave + 4) * 1024;

  const int wm = wave >> 1;
  const int wn = wave & 1;
  const int fr = lane & 15;
  const int fq = lane >> 4;
  const bf16* pA = lA + (wm * 64 + fr) * 32 + fq * 8;
  const bf16* pB = lB + (wn * 64 + fr) * 32 + fq * 8;

  f32x4 acc[4][4];
#pragma unroll
  for (int i = 0; i < 4; ++i)
#pragma unroll
    for (int j = 0; j < 4; ++j)
#pragma unroll
      for (int k = 0; k < 4; ++k) acc[i][j][k] = 0.f;

  for (int kt = 0; kt < D_MODEL / 32; ++kt) {
    cp16(dA0, srcA0); cp16(dA1, srcA1);
    cp16(dB0, srcB0); cp16(dB1, srcB1);
    srcA0 += 32; srcA1 += 32; srcB0 += 32; srcB1 += 32;
    __syncthreads();
    bf16x8 a[4];
#pragma unroll
    for (int fm = 0; fm < 4; ++fm) a[fm] = *(const bf16x8*)(pA + fm * 16 * 32);
#pragma unroll
    for (int fn = 0; fn < 4; ++fn) {
      bf16x8 b = *(const bf16x8*)(pB + fn * 16 * 32);
#pragma unroll
      for (int fm = 0; fm < 4; ++fm) acc[fm][fn] = mfma16(a[fm], b, acc[fm][fn]);
    }
    __syncthreads();
  }

  const int hbase = offsets[e] + row0;
#pragma unroll
  for (int fm = 0; fm < 4; ++fm) {
#pragma unroll
    for (int fn = 0; fn < 4; ++fn) {
#pragma unroll
      for (int i = 0; i < 4; ++i) {
        int m = wm * 64 + fm * 16 + fq * 4 + i;   // C/D: row = quad*4+reg
        if (row0 + m < cnt) {
          int col = c0 + wn * 64 + fn * 16 + fr;  // C/D: col = lane&15
          GU[(size_t)(hbase + m) * D_GU + col] = (bf16)acc[fm][fn][i];
        }
      }
    }
  }
}

// ====== SwiGLU in-place: GU[r][j] (gate half) <- silu(GU[r][2048+j]) * GU[r][j] ======
__global__ __launch_bounds__(256) void swiglu_kernel(bf16* __restrict__ GU)
{
  // 8192 rows x 2048 cols, 8 cols per thread (all compacted rows are valid: sum(counts)=8192)
  const int idx = blockIdx.x * 256 + threadIdx.x;
  const int row = idx >> 8;                 // 256 groups of 8 per row
  const int col = (idx & 255) * 8;
  bf16* g = GU + (size_t)row * D_GU + col;
  bf16x8 g8 = *(const bf16x8*)g;
  bf16x8 u8 = *(const bf16x8*)(g + D_FF);
  bf16x8 h;
#pragma unroll
  for (int j = 0; j < 8; ++j) {
    float u = (float)u8[j];
    float gg = (float)g8[j];
    h[j] = (bf16)(gg * u / (1.f + expf(-u)));
  }
  *(bf16x8*)g = h;
}

// ====== GEMM2: H(=GU gate half, pitch 4096) @ Wd_b^T -> atomicAdd(w*acc) into fp32 out ======
__global__ __launch_bounds__(256, 2) void gemm2_kernel(
    const bf16* __restrict__ GU, const bf16* __restrict__ wdb,
    const int* __restrict__ counts, const int* __restrict__ offsets,
    const int* __restrict__ ids, const float* __restrict__ wts,
    float* __restrict__ out)
{
  const int e = blockIdx.z;
  const int cnt = counts[e];
  const int row0 = blockIdx.y * 128;
  if (row0 >= cnt) return;
  const int c0 = blockIdx.x * 128;              // output col tile in [0, 1024)
  const int base = offsets[e];

  __shared__ bf16 lA[128 * 32];
  __shared__ bf16 lB[128 * 32];

  const int tid  = threadIdx.x;
  const int lane = tid & 63;
  const int wave = tid >> 6;
  const int l4 = lane >> 2;
  const int kb = (lane & 3) * 8;

  const int ra0 = wave * 16 + l4;
  const int ra1 = (wave + 4) * 16 + l4;
  const int m0 = min(row0 + ra0, cnt - 1);
  const int m1 = min(row0 + ra1, cnt - 1);
  const bf16* srcA0 = GU + (size_t)(base + m0) * D_GU + kb;   // pitch 4096, K in [0,2048)
  const bf16* srcA1 = GU + (size_t)(base + m1) * D_GU + kb;
  const bf16* wde = wdb + (size_t)e * D_MODEL * D_FF;
  const bf16* srcB0 = wde + (size_t)(c0 + ra0) * D_FF + kb;
  const bf16* srcB1 = wde + (size_t)(c0 + ra1) * D_FF + kb;

  char* dA0 = (char*)lA + wave * 1024;
  char* dA1 = (char*)lA + (wave + 4) * 1024;
  char* dB0 = (char*)lB + wave * 1024;
  char* dB1 = (char*)lB + (wave + 4) * 1024;

  const int wm = wave >> 1;
  const int wn = wave & 1;
  const int fr = lane & 15;
  const int fq = lane >> 4;
  const bf16* pA = lA + (wm * 64 + fr) * 32 + fq * 8;
  const bf16* pB = lB + (wn * 64 + fr) * 32 + fq * 8;

  f32x4 acc[4][4];
#pragma unroll
  for (int i = 0; i < 4; ++i)
#pragma unroll
    for (int j = 0; j < 4; ++j)
#pragma unroll
      for (int k = 0; k < 4; ++k) acc[i][j][k] = 0.f;

  for (int kt = 0; kt < D_FF / 32; ++kt) {
    cp16(dA0, srcA0); cp16(dA1, srcA1);
    cp16(dB0, srcB0); cp16(dB1, srcB1);
    srcA0 += 32; srcA1 += 32; srcB0 += 32; srcB1 += 32;
    __syncthreads();
    bf16x8 a[4];
#pragma unroll
    for (int fm = 0; fm < 4; ++fm) a[fm] = *(const bf16x8*)(pA + fm * 16 * 32);
#pragma unroll
    for (int fn = 0; fn < 4; ++fn) {
      bf16x8 b = *(const bf16x8*)(pB + fn * 16 * 32);
#pragma unroll
      for (int fm = 0; fm < 4; ++fm) acc[fm][fn] = mfma16(a[fm], b, acc[fm][fn]);
    }
    __syncthreads();
  }

  const int* ide = ids + e * N_TOK;
  const float* wte = wts + e * N_TOK;
#pragma unroll
  for (int fm = 0; fm < 4; ++fm) {
#pragma unroll
    for (int i = 0; i < 4; ++i) {
      int m = wm * 64 + fm * 16 + fq * 4 + i;
      if (row0 + m < cnt) {
        int   tok = ide[row0 + m];
        float w   = wte[row0 + m];
        float* orow = out + (size_t)tok * D_MODEL;
#pragma unroll
        for (int fn = 0; fn < 4; ++fn) {
          int col = c0 + wn * 64 + fn * 16 + fr;
          atomicAdd(orow + col, w * acc[fm][fn][i]);
        }
      }
    }
  }
}

// =========================================================================================
extern "C" void kernel_launch(void* const* d_in, const int* in_sizes, int n_in,
                              void* d_out, int out_size, void* d_ws, size_t ws_size,
                              hipStream_t stream) {
  const float* x   = (const float*)d_in[0];
  const float* wr  = (const float*)d_in[1];
  const float* wgu = (const float*)d_in[2];
  const float* wd  = (const float*)d_in[3];
  float* out = (float*)d_out;

  char* ws = (char*)d_ws;
  // workspace layout — 136.5 MB total (== round-4 fast-path NEED, proven available)
  int*   counts  = (int*)ws;                             // 32 B
  int*   offsets = (int*)(ws + 64);                      // 32 B
  int*   ids     = (int*)(ws + 4096);                    // 128 KB
  float* wts     = (float*)(ws + 4096 + 131072);         // 128 KB
  bf16*  xb      = (bf16*)(ws + 524288);                 // 8 MB
  bf16*  wgub    = (bf16*)(ws + 524288 + 8388608);       // 64 MB (reused for wdb after gemm1a)
  bf16*  wdb     = wgub;                                 // 32 MB alias (wgub dead post-gemm1a)
  bf16*  GU      = (bf16*)(ws + 524288 + 8388608 + 67108864);  // 8192 x 4096 bf16 = 64 MB

  hipMemsetAsync(counts, 0, 64, stream);
  hipMemsetAsync(out, 0, (size_t)N_TOK * D_MODEL * sizeof(float), stream);
  router_kernel<<<N_TOK / 32, 256, 0, stream>>>(x, wr, counts, ids, wts, xb);
  offsets_kernel<<<1, 64, 0, stream>>>(counts, offsets);
  cvt_kernel<<<2048, 256, 0, stream>>>(wgu, wgub, (N_EXP * D_GU * D_MODEL) / 8);
  gemm1a_kernel<<<dim3(D_GU / 128, N_TOK / 128, N_EXP), 256, 0, stream>>>(
      xb, wgub, counts, offsets, ids, GU);
  swiglu_kernel<<<(8192 * (D_FF / 8)) / 256, 256, 0, stream>>>(GU);
  cvt_kernel<<<2048, 256, 0, stream>>>(wd, wdb, (N_EXP * D_MODEL * D_FF) / 8);
  gemm2_kernel<<<dim3(D_MODEL / 128, N_TOK / 128, N_EXP), 256, 0, stream>>>(
      GU, wdb, counts, offsets, ids, wts, out);
}